// Round 2
// baseline (116.293 us; speedup 1.0000x reference)
//
#include <hip/hip_runtime.h>

// GaussianBlurND: depthwise 9x9 Gaussian blur (sigma=2) on [16,64,256,256] f32,
// out = blur(x) / blur(ones), separable + factorized edge correction.
//
// R1 design: barrier-free, LDS-free.
//   - one WAVE covers a full row (64 lanes x float4 = 256 cols)
//   - vertical 9-tap: rolling window of 9 float4 registers (each input row
//     loaded exactly once per strip, 16 B/lane coalesced)
//   - horizontal 9-tap: own float4 + left/right neighbor via __shfl (2 lanes),
//     zeroed at image edges; no LDS, no __syncthreads
//   - 4 row-strips of 64 per plane (one per wave in a 256-thread block);
//     strip halo costs +9.4% fetch but removes all inter-wave coupling
//   - 4-row group prefetch for memory-level parallelism

#define HH 256
#define WW 256
#define W4 (WW / 4)        // row pitch in float4
#define STRIPS 4
#define SROWS (HH / STRIPS)

// Normalized 1-D Gaussian taps, sigma=2, k=9.
#define G0 0.02763055f
#define G1 0.06628225f
#define G2 0.12383154f
#define G3 0.18017382f
#define G4 0.20416361f

__device__ __forceinline__ float4 shfl4(float4 v, int src) {
    float4 r;
    r.x = __shfl(v.x, src, 64);
    r.y = __shfl(v.y, src, 64);
    r.z = __shfl(v.z, src, 64);
    r.w = __shfl(v.w, src, 64);
    return r;
}

__global__ __launch_bounds__(256) void gauss_blur_kernel(
    const float* __restrict__ x, float* __restrict__ out)
{
    const float G[9] = {G0, G1, G2, G3, G4, G3, G2, G1, G0};

    const int plane = blockIdx.x;
    const int wid   = threadIdx.x >> 6;    // strip 0..3
    const int lane  = threadIdx.x & 63;    // column quad 0..63
    const float4* __restrict__ src = (const float4*)(x + (size_t)plane * (HH * WW));
    float4* __restrict__ dst       = (float4*)(out + (size_t)plane * (HH * WW));
    const int r0 = wid * SROWS;

    // Per-lane horizontal edge correction (≠1 only on lanes 0 and 63).
    float4 inv_wx = make_float4(1.f, 1.f, 1.f, 1.f);
    if (lane == 0 || lane == 63) {
        float w[4];
        #pragma unroll
        for (int j = 0; j < 4; ++j) {
            const int c = lane * 4 + j;
            float s = 0.f;
            #pragma unroll
            for (int i = 0; i < 9; ++i) {
                const int q = c + i - 4;
                if (q >= 0 && q < WW) s += G[i];
            }
            w[j] = 1.f / s;
        }
        inv_wx = make_float4(w[0], w[1], w[2], w[3]);
    }

    auto ldrow = [&](int r) -> float4 {
        return ((unsigned)r < (unsigned)HH) ? src[r * W4 + lane]
                                            : make_float4(0.f, 0.f, 0.f, 0.f);
    };

    // Rolling vertical window: win[i] = row (r + i - 4) for current output row r.
    float4 win[9];
    #pragma unroll
    for (int i = 0; i < 9; ++i) win[i] = ldrow(r0 + i - 4);

    auto step = [&](int r, float4 nxt) {
        // ---- vertical 9-tap ----
        float4 v;
        v.x = G[0] * win[0].x; v.y = G[0] * win[0].y;
        v.z = G[0] * win[0].z; v.w = G[0] * win[0].w;
        #pragma unroll
        for (int i = 1; i < 9; ++i) {
            v.x = fmaf(G[i], win[i].x, v.x);
            v.y = fmaf(G[i], win[i].y, v.y);
            v.z = fmaf(G[i], win[i].z, v.z);
            v.w = fmaf(G[i], win[i].w, v.w);
        }
        // ---- neighbor quads via shuffle (zero outside image) ----
        float4 vm = shfl4(v, lane - 1);
        float4 vp = shfl4(v, lane + 1);
        if (lane == 0)  vm = make_float4(0.f, 0.f, 0.f, 0.f);
        if (lane == 63) vp = make_float4(0.f, 0.f, 0.f, 0.f);
        const float s[12] = {vm.x, vm.y, vm.z, vm.w,
                             v.x,  v.y,  v.z,  v.w,
                             vp.x, vp.y, vp.z, vp.w};
        // ---- horizontal 9-tap ----
        float o[4];
        #pragma unroll
        for (int j = 0; j < 4; ++j) {
            float a = G[0] * s[j];
            #pragma unroll
            for (int i = 1; i < 9; ++i) a = fmaf(G[i], s[j + i], a);
            o[j] = a;
        }
        // ---- vertical edge correction (wave-uniform branch) ----
        float iwy = 1.f;
        if (r < 4 || r >= HH - 4) {
            float wy = 0.f;
            #pragma unroll
            for (int i = 0; i < 9; ++i) {
                const int q = r + i - 4;
                if (q >= 0 && q < HH) wy += G[i];
            }
            iwy = 1.f / wy;
        }
        dst[r * W4 + lane] = make_float4(o[0] * inv_wx.x * iwy,
                                         o[1] * inv_wx.y * iwy,
                                         o[2] * inv_wx.z * iwy,
                                         o[3] * inv_wx.w * iwy);
        // ---- roll the window ----
        #pragma unroll
        for (int i = 0; i < 8; ++i) win[i] = win[i + 1];
        win[8] = nxt;
    };

    for (int rr = 0; rr < SROWS; rr += 4) {
        const int r = r0 + rr;
        // group prefetch: 4 next rows issued back-to-back (4 loads in flight)
        float4 n0 = ldrow(r + 5);
        float4 n1 = ldrow(r + 6);
        float4 n2 = ldrow(r + 7);
        float4 n3 = ldrow(r + 8);
        step(r,     n0);
        step(r + 1, n1);
        step(r + 2, n2);
        step(r + 3, n3);
    }
}

extern "C" void kernel_launch(void* const* d_in, const int* in_sizes, int n_in,
                              void* d_out, int out_size, void* d_ws, size_t ws_size,
                              hipStream_t stream)
{
    const float* x = (const float*)d_in[0];
    float* out = (float*)d_out;
    const int nplanes = in_sizes[0] / (HH * WW);  // 16*64 = 1024
    gauss_blur_kernel<<<nplanes, 256, 0, stream>>>(x, out);
}

// Round 3
// 99.338 us; speedup vs baseline: 1.1707x; 1.1707x over previous
//
#include <hip/hip_runtime.h>

// GaussianBlurND: depthwise 9x9 Gaussian blur (sigma=2) on [16,64,256,256] f32,
// out = blur(x) / blur(ones), separable + factorized edge correction.
//
// R2: R1 (wave-per-row-strip, rolling register window, shuffle-based
// horizontal pass, no LDS/barriers) plus:
//   - nontemporal stores (write stream has zero reuse; keep it out of L2)
//   - 2-group-deep double-buffered prefetch: 8 rows in flight, issue->use
//     distance ~5 steps (~1300 issue-cy) > 900-cy HBM latency
//   - strip-end clamp so deep prefetch never fetches rows the strip doesn't need

#define HH 256
#define WW 256
#define W4 (WW / 4)
#define STRIPS 4
#define SROWS (HH / STRIPS)

// Normalized 1-D Gaussian taps, sigma=2, k=9.
#define G0 0.02763055f
#define G1 0.06628225f
#define G2 0.12383154f
#define G3 0.18017382f
#define G4 0.20416361f

typedef float f4 __attribute__((ext_vector_type(4)));

__device__ __forceinline__ f4 shfl4(f4 v, int src) {
    f4 r;
    r.x = __shfl(v.x, src, 64);
    r.y = __shfl(v.y, src, 64);
    r.z = __shfl(v.z, src, 64);
    r.w = __shfl(v.w, src, 64);
    return r;
}

__global__ __launch_bounds__(256) void gauss_blur_kernel(
    const float* __restrict__ x, float* __restrict__ out)
{
    const float G[9] = {G0, G1, G2, G3, G4, G3, G2, G1, G0};

    const int plane = blockIdx.x;
    const int wid   = threadIdx.x >> 6;    // strip 0..3
    const int lane  = threadIdx.x & 63;    // column quad
    const f4* __restrict__ src = (const f4*)(x + (size_t)plane * (HH * WW));
    f4* __restrict__ dst       = (f4*)(out + (size_t)plane * (HH * WW));
    const int r0   = wid * SROWS;
    const int rmax = (r0 + SROWS + 4 < HH) ? (r0 + SROWS + 4) : HH; // last row this strip needs

    // Per-lane horizontal edge correction (≠1 only on lanes 0 and 63).
    f4 inv_wx = (f4){1.f, 1.f, 1.f, 1.f};
    if (lane == 0 || lane == 63) {
        float w[4];
        #pragma unroll
        for (int j = 0; j < 4; ++j) {
            const int c = lane * 4 + j;
            float s = 0.f;
            #pragma unroll
            for (int i = 0; i < 9; ++i) {
                const int q = c + i - 4;
                if (q >= 0 && q < WW) s += G[i];
            }
            w[j] = 1.f / s;
        }
        inv_wx = (f4){w[0], w[1], w[2], w[3]};
    }

    auto ldrow = [&](int r) -> f4 {
        return ((unsigned)r < (unsigned)rmax) ? src[r * W4 + lane]
                                              : (f4){0.f, 0.f, 0.f, 0.f};
    };

    // Rolling window: win[i] = row (r + i - 4) for current output row r.
    f4 win[9];
    #pragma unroll
    for (int i = 0; i < 9; ++i) win[i] = ldrow(r0 + i - 4);

    auto step = [&](int r, f4 nxt) {
        // vertical 9-tap
        f4 v = G[0] * win[0];
        #pragma unroll
        for (int i = 1; i < 9; ++i) {
            v.x = fmaf(G[i], win[i].x, v.x);
            v.y = fmaf(G[i], win[i].y, v.y);
            v.z = fmaf(G[i], win[i].z, v.z);
            v.w = fmaf(G[i], win[i].w, v.w);
        }
        // neighbor quads via shuffle (zero outside image)
        f4 vm = shfl4(v, lane - 1);
        f4 vp = shfl4(v, lane + 1);
        if (lane == 0)  vm = (f4){0.f, 0.f, 0.f, 0.f};
        if (lane == 63) vp = (f4){0.f, 0.f, 0.f, 0.f};
        const float s[12] = {vm.x, vm.y, vm.z, vm.w,
                             v.x,  v.y,  v.z,  v.w,
                             vp.x, vp.y, vp.z, vp.w};
        // horizontal 9-tap
        float o[4];
        #pragma unroll
        for (int j = 0; j < 4; ++j) {
            float a = G[0] * s[j];
            #pragma unroll
            for (int i = 1; i < 9; ++i) a = fmaf(G[i], s[j + i], a);
            o[j] = a;
        }
        // vertical edge correction (wave-uniform branch)
        float iwy = 1.f;
        if (r < 4 || r >= HH - 4) {
            float wy = 0.f;
            #pragma unroll
            for (int i = 0; i < 9; ++i) {
                const int q = r + i - 4;
                if (q >= 0 && q < HH) wy += G[i];
            }
            iwy = 1.f / wy;
        }
        f4 res = (f4){o[0] * inv_wx.x * iwy, o[1] * inv_wx.y * iwy,
                      o[2] * inv_wx.z * iwy, o[3] * inv_wx.w * iwy};
        __builtin_nontemporal_store(res, &dst[r * W4 + lane]);
        // roll the window
        #pragma unroll
        for (int i = 0; i < 8; ++i) win[i] = win[i + 1];
        win[8] = nxt;
    };

    // Double-buffered 2-group-deep pipeline: pa holds rows r+5..r+8,
    // pb is issued for rows r+9..r+12 before pa is consumed.
    f4 pa0 = ldrow(r0 + 5), pa1 = ldrow(r0 + 6), pa2 = ldrow(r0 + 7), pa3 = ldrow(r0 + 8);

    for (int rr = 0; rr < SROWS; rr += 8) {
        const int r = r0 + rr;
        f4 pb0 = ldrow(r + 9),  pb1 = ldrow(r + 10), pb2 = ldrow(r + 11), pb3 = ldrow(r + 12);
        step(r,     pa0);
        step(r + 1, pa1);
        step(r + 2, pa2);
        step(r + 3, pa3);
        pa0 = ldrow(r + 13); pa1 = ldrow(r + 14); pa2 = ldrow(r + 15); pa3 = ldrow(r + 16);
        step(r + 4, pb0);
        step(r + 5, pb1);
        step(r + 6, pb2);
        step(r + 7, pb3);
    }
}

extern "C" void kernel_launch(void* const* d_in, const int* in_sizes, int n_in,
                              void* d_out, int out_size, void* d_ws, size_t ws_size,
                              hipStream_t stream)
{
    const float* x = (const float*)d_in[0];
    float* out = (float*)d_out;
    const int nplanes = in_sizes[0] / (HH * WW);  // 16*64 = 1024
    gauss_blur_kernel<<<nplanes, 256, 0, stream>>>(x, out);
}

// Round 5
// 88.241 us; speedup vs baseline: 1.3179x; 1.1258x over previous
//
#include <hip/hip_runtime.h>

// GaussianBlurND: depthwise 9x9 Gaussian blur (sigma=2) on [16,64,256,256] f32,
// out = blur(x) / blur(ones), separable + factorized edge correction.
//
// R4: R3 with the 3-deep pipeline rotation FIXED.
// Invariant at iteration entry (base row r):
//   a = rows r+5..r+8, b = r+9..r+12, c = r+13..r+16.
// During the iteration issue t = r+17..r+20, u = r+21..r+24;
// rotate (a,b,c) <- (c,t,u).   [R3 bug: rotated a<-fresh, b<-c => shifted rows]
//   - 2 strips of 128 rows per plane, block = 128 threads (2 waves)
//   - rolling 9-row register window, shuffle horizontal pass, no LDS/barriers
//   - nontemporal batched stores

#define HH 256
#define WW 256
#define W4 (WW / 4)
#define STRIPS 2
#define SROWS (HH / STRIPS)   // 128

// Normalized 1-D Gaussian taps, sigma=2, k=9.
#define G0 0.02763055f
#define G1 0.06628225f
#define G2 0.12383154f
#define G3 0.18017382f
#define G4 0.20416361f

typedef float f4 __attribute__((ext_vector_type(4)));

__device__ __forceinline__ f4 shfl4(f4 v, int src) {
    f4 r;
    r.x = __shfl(v.x, src, 64);
    r.y = __shfl(v.y, src, 64);
    r.z = __shfl(v.z, src, 64);
    r.w = __shfl(v.w, src, 64);
    return r;
}

__global__ __launch_bounds__(128) void gauss_blur_kernel(
    const float* __restrict__ x, float* __restrict__ out)
{
    const float G[9] = {G0, G1, G2, G3, G4, G3, G2, G1, G0};

    const int plane = blockIdx.x;
    const int wid   = threadIdx.x >> 6;    // strip 0..1
    const int lane  = threadIdx.x & 63;    // column quad
    const f4* __restrict__ src = (const f4*)(x + (size_t)plane * (HH * WW));
    f4* __restrict__ dst       = (f4*)(out + (size_t)plane * (HH * WW));
    const int r0   = wid * SROWS;
    const int rmax = (r0 + SROWS + 4 < HH) ? (r0 + SROWS + 4) : HH;

    // Per-lane horizontal edge correction (≠1 only on lanes 0 and 63).
    f4 inv_wx = (f4){1.f, 1.f, 1.f, 1.f};
    if (lane == 0 || lane == 63) {
        float w[4];
        #pragma unroll
        for (int j = 0; j < 4; ++j) {
            const int c = lane * 4 + j;
            float s = 0.f;
            #pragma unroll
            for (int i = 0; i < 9; ++i) {
                const int q = c + i - 4;
                if (q >= 0 && q < WW) s += G[i];
            }
            w[j] = 1.f / s;
        }
        inv_wx = (f4){w[0], w[1], w[2], w[3]};
    }

    auto ldrow = [&](int r) -> f4 {
        return ((unsigned)r < (unsigned)rmax) ? src[r * W4 + lane]
                                              : (f4){0.f, 0.f, 0.f, 0.f};
    };

    // Rolling window: win[i] = row (r + i - 4) for current output row r.
    f4 win[9];
    #pragma unroll
    for (int i = 0; i < 9; ++i) win[i] = ldrow(r0 + i - 4);

    // step: vertical tap + shuffle + horizontal tap + correction; returns result.
    auto step = [&](int r, f4 nxt) -> f4 {
        f4 v = G[0] * win[0];
        #pragma unroll
        for (int i = 1; i < 9; ++i) {
            v.x = fmaf(G[i], win[i].x, v.x);
            v.y = fmaf(G[i], win[i].y, v.y);
            v.z = fmaf(G[i], win[i].z, v.z);
            v.w = fmaf(G[i], win[i].w, v.w);
        }
        f4 vm = shfl4(v, lane - 1);
        f4 vp = shfl4(v, lane + 1);
        if (lane == 0)  vm = (f4){0.f, 0.f, 0.f, 0.f};
        if (lane == 63) vp = (f4){0.f, 0.f, 0.f, 0.f};
        const float s[12] = {vm.x, vm.y, vm.z, vm.w,
                             v.x,  v.y,  v.z,  v.w,
                             vp.x, vp.y, vp.z, vp.w};
        float o[4];
        #pragma unroll
        for (int j = 0; j < 4; ++j) {
            float a = G[0] * s[j];
            #pragma unroll
            for (int i = 1; i < 9; ++i) a = fmaf(G[i], s[j + i], a);
            o[j] = a;
        }
        float iwy = 1.f;                       // wave-uniform branch
        if (r < 4 || r >= HH - 4) {
            float wy = 0.f;
            #pragma unroll
            for (int i = 0; i < 9; ++i) {
                const int q = r + i - 4;
                if (q >= 0 && q < HH) wy += G[i];
            }
            iwy = 1.f / wy;
        }
        #pragma unroll
        for (int i = 0; i < 8; ++i) win[i] = win[i + 1];
        win[8] = nxt;
        return (f4){o[0] * inv_wx.x * iwy, o[1] * inv_wx.y * iwy,
                    o[2] * inv_wx.z * iwy, o[3] * inv_wx.w * iwy};
    };

    // 3-deep pipeline, entry invariant: a=r+5..r+8, b=r+9..r+12, c=r+13..r+16.
    f4 a0 = ldrow(r0 + 5),  a1 = ldrow(r0 + 6),  a2 = ldrow(r0 + 7),  a3 = ldrow(r0 + 8);
    f4 b0 = ldrow(r0 + 9),  b1 = ldrow(r0 + 10), b2 = ldrow(r0 + 11), b3 = ldrow(r0 + 12);
    f4 c0 = ldrow(r0 + 13), c1 = ldrow(r0 + 14), c2 = ldrow(r0 + 15), c3 = ldrow(r0 + 16);

    for (int rr = 0; rr < SROWS; rr += 8) {
        const int r = r0 + rr;
        // issue next-next group (-> b' after rotation)
        f4 t0 = ldrow(r + 17), t1 = ldrow(r + 18), t2 = ldrow(r + 19), t3 = ldrow(r + 20);
        // group 1: consume a (rows r..r+3), batch stores
        f4 o0 = step(r,     a0);
        f4 o1 = step(r + 1, a1);
        f4 o2 = step(r + 2, a2);
        f4 o3 = step(r + 3, a3);
        __builtin_nontemporal_store(o0, &dst[(r    ) * W4 + lane]);
        __builtin_nontemporal_store(o1, &dst[(r + 1) * W4 + lane]);
        __builtin_nontemporal_store(o2, &dst[(r + 2) * W4 + lane]);
        __builtin_nontemporal_store(o3, &dst[(r + 3) * W4 + lane]);
        // issue next-next-next group (-> c' after rotation)
        f4 u0 = ldrow(r + 21), u1 = ldrow(r + 22), u2 = ldrow(r + 23), u3 = ldrow(r + 24);
        // group 2: consume b (rows r+4..r+7), batch stores
        o0 = step(r + 4, b0);
        o1 = step(r + 5, b1);
        o2 = step(r + 6, b2);
        o3 = step(r + 7, b3);
        __builtin_nontemporal_store(o0, &dst[(r + 4) * W4 + lane]);
        __builtin_nontemporal_store(o1, &dst[(r + 5) * W4 + lane]);
        __builtin_nontemporal_store(o2, &dst[(r + 6) * W4 + lane]);
        __builtin_nontemporal_store(o3, &dst[(r + 7) * W4 + lane]);
        // rotate: (a,b,c) <- (c,t,u)
        a0 = c0; a1 = c1; a2 = c2; a3 = c3;
        b0 = t0; b1 = t1; b2 = t2; b3 = t3;
        c0 = u0; c1 = u1; c2 = u2; c3 = u3;
    }
}

extern "C" void kernel_launch(void* const* d_in, const int* in_sizes, int n_in,
                              void* d_out, int out_size, void* d_ws, size_t ws_size,
                              hipStream_t stream)
{
    const float* x = (const float*)d_in[0];
    float* out = (float*)d_out;
    const int nplanes = in_sizes[0] / (HH * WW);  // 16*64 = 1024
    gauss_blur_kernel<<<nplanes, 128, 0, stream>>>(x, out);
}